// Round 5
// baseline (1055.755 us; speedup 1.0000x reference)
//
#include <hip/hip_runtime.h>
#include <math.h>

#define T_SAMPLES 96000
#define NFRAMES 801
#define NBINS 513
#define EPS32 1.1920928955078125e-07f

typedef _Float16 f16;
typedef f16 f16x2 __attribute__((ext_vector_type(2)));
typedef f16 f16x8 __attribute__((ext_vector_type(8)));
typedef float f32x4 __attribute__((ext_vector_type(4)));

// ---------------------------------------------------------------- STFT ----
__global__ __launch_bounds__(512) void stft_kernel(const float* __restrict__ y,
                                                   float* __restrict__ mag)
{
    int t = blockIdx.x;   // frame 0..800
    int b = blockIdx.y;   // batch 0..3
    int tid = threadIdx.x;

    __shared__ float2 buf[2][1024];

    const float* yb = y + (size_t)b * T_SAMPLES;
    for (int n = tid; n < 1024; n += 512) {
        int j = t * 120 + n - 512;          // reflect pad 512 both sides
        if (j < 0) j = -j;
        if (j >= T_SAMPLES) j = 2 * T_SAMPLES - 2 - j;
        float v = yb[j];
        int np_ = n - 212;                  // window placed at lp=212, len 600
        float w = 0.0f;
        if (np_ >= 0 && np_ < 600)
            w = 0.5f * (1.0f - cospif((float)np_ * (1.0f / 300.0f)));
        buf[0][n] = make_float2(v * w, 0.0f);
    }
    __syncthreads();

    int srcb = 0;
    #pragma unroll
    for (int stage = 0; stage < 10; ++stage) {
        int m  = 1 << stage;
        int jm = (tid >> stage) << stage;   // j*m
        float jf = (float)jm * (1.0f / 512.0f);
        float wr = cospif(jf);
        float wi = -sinpif(jf);             // e^{-i pi j/l}
        float2 a  = buf[srcb][tid];
        float2 bb = buf[srcb][tid + 512];
        float2 s  = make_float2(a.x + bb.x, a.y + bb.y);
        float2 d  = make_float2(a.x - bb.x, a.y - bb.y);
        float2 dw = make_float2(d.x * wr - d.y * wi, d.x * wi + d.y * wr);
        buf[srcb ^ 1][tid + jm]     = s;
        buf[srcb ^ 1][tid + jm + m] = dw;
        __syncthreads();
        srcb ^= 1;
    }

    float2 v = buf[srcb][tid];
    float msq = v.x * v.x + v.y * v.y;
    mag[((size_t)b * NBINS + tid) * NFRAMES + t] = sqrtf(fmaxf(msq, EPS32));
    if (tid == 0) {
        float2 v5 = buf[srcb][512];
        float m5 = v5.x * v5.x + v5.y * v5.y;
        mag[((size_t)b * NBINS + 512) * NFRAMES + t] = sqrtf(fmaxf(m5, EPS32));
    }
}

// ---------------------------------------------------------- weight norm ----
__global__ __launch_bounds__(256) void wnorm_kernel(const float* __restrict__ v,
                                                    const float* __restrict__ g,
                                                    float* __restrict__ out, int per_o)
{
    int o = blockIdx.x;
    int tid = threadIdx.x;
    __shared__ float red[256];
    const float* vo = v + (size_t)o * per_o;
    float s = 0.f;
    for (int i = tid; i < per_o; i += 256) { float x = vo[i]; s = fmaf(x, x, s); }
    red[tid] = s;
    __syncthreads();
    for (int k = 128; k > 0; k >>= 1) {
        if (tid < k) red[tid] += red[tid + k];
        __syncthreads();
    }
    float scale = g[o] / sqrtf(red[0]);
    for (int i = tid; i < per_o; i += 256) out[(size_t)o * per_o + i] = vo[i] * scale;
}

// -------------------------------------------------------------- pack A ----
template<int KW>
__global__ __launch_bounds__(256) void packA_kernel(const float* __restrict__ wn,
                                                    f16* __restrict__ out)
{
    int idx = blockIdx.x * 256 + threadIdx.x;
    if (idx >= 3 * KW * 1024) return;
    int j   = idx & 7;
    int l   = (idx >> 3) & 63;
    int oh  = (idx >> 9) & 1;
    int tap = idx >> 10;
    int df  = tap / KW, kw = tap - df * KW;
    int o = oh * 16 + (l & 15);
    int c = ((l >> 4) << 3) + j;
    out[idx] = (f16)wn[((o * 32 + c) * 3 + df) * KW + kw];
}

// -------------------------------------------------------- harmonic conv ----
__global__ __launch_bounds__(256) void harmonic_kernel(const float* __restrict__ mag,
                                                       const float* __restrict__ wn,
                                                       const float* __restrict__ bias,
                                                       float* __restrict__ out,
                                                       float fr4, float fr5)
{
    int f = blockIdx.x;
    int b = blockIdx.y;
    int tid = threadIdx.x;

    __shared__ float rows[3][808];

    const float* mb = mag + (size_t)b * NBINS * NFRAMES;

    for (int i = tid; i < 808; i += 256) {
        int tt = i - 3;
        bool ok = (tt >= 0) && (tt < NFRAMES);
        float m336 = (ok && f >= 336) ? mb[(size_t)(f - 336) * NFRAMES + tt] : 0.f;
        float m337 = (ok && f >= 337) ? mb[(size_t)(f - 337) * NFRAMES + tt] : 0.f;
        float m154 = (ok && f >= 154) ? mb[(size_t)(f - 154) * NFRAMES + tt] : 0.f;
        float m155 = (ok && f >= 155) ? mb[(size_t)(f - 155) * NFRAMES + tt] : 0.f;
        float m0   = ok ? mb[(size_t)f * NFRAMES + tt] : 0.f;
        rows[0][i] = (1.f - fr4) * m336 + fr4 * m337;
        rows[1][i] = (1.f - fr5) * m154 + fr5 * m155;
        rows[2][i] = m0;
    }
    __syncthreads();

    int t0 = tid * 4;
    float win[3][10];
    #pragma unroll
    for (int r = 0; r < 3; ++r)
        #pragma unroll
        for (int k = 0; k < 10; ++k) {
            int idx = t0 + k; if (idx > 807) idx = 807;
            win[r][k] = rows[r][idx];
        }

    bool full = (t0 + 3 < NFRAMES);
    bool any  = (t0 < NFRAMES);
    if (!any) return;

    size_t obase = (((size_t)b * 32) * NBINS + f) * NFRAMES + t0;
    for (int o = 0; o < 32; ++o) {
        float acc0 = bias[o], acc1 = acc0, acc2 = acc0, acc3 = acc0;
        #pragma unroll
        for (int r = 0; r < 3; ++r) {
            const float* wr = wn + (o * 7 + 4 + r) * 7;
            #pragma unroll
            for (int kw = 0; kw < 7; ++kw) {
                float w = wr[kw];
                acc0 = fmaf(win[r][kw],     w, acc0);
                acc1 = fmaf(win[r][kw + 1], w, acc1);
                acc2 = fmaf(win[r][kw + 2], w, acc2);
                acc3 = fmaf(win[r][kw + 3], w, acc3);
            }
        }
        acc0 = (acc0 > 0.f) ? acc0 : 0.1f * acc0;
        acc1 = (acc1 > 0.f) ? acc1 : 0.1f * acc1;
        acc2 = (acc2 > 0.f) ? acc2 : 0.1f * acc2;
        acc3 = (acc3 > 0.f) ? acc3 : 0.1f * acc3;
        float* p = out + obase + (size_t)o * NBINS * NFRAMES;
        if (full) {
            f32x4 v = {acc0, acc1, acc2, acc3};
            *reinterpret_cast<f32x4*>(p) = v;
        } else {
            int nrem = NFRAMES - t0;           // 1..3
            p[0] = acc0;
            if (nrem > 1) p[1] = acc1;
            if (nrem > 2) p[2] = acc2;
        }
    }
}

// ------------------------------------------------ persistent MFMA conv ----
// 32ch -> 32ch, kernel 3 x KW, freq pad 1, time pad PW, time stride STRIDE.
// Persistent blocks, double-buffered LDS. Per tile iteration:
//   issue next-tile global loads (regs) -> compute current (ds_read+MFMA)
//   -> store -> cvt+ds_write next -> lgkmcnt(0) + raw s_barrier.
// Raw barrier (not __syncthreads) keeps next-tile loads in flight (T14/T3).
template<int KW, int STRIDE, int PW, int NTB, bool DO_LRELU>
__global__ __launch_bounds__(256, 2) void conv_mfma_persist(
    const float* __restrict__ in, const f16* __restrict__ Ap,
    const float* __restrict__ bias, float* __restrict__ out,
    int Tin, int Tout)
{
    constexpr int NT    = 64;
    constexpr int TR    = NT * STRIDE + KW - 1;
    constexpr int TRP   = (TR + 1) & ~1;
    constexpr int NTAPS = 3 * KW;
    constexpr int ROWB  = TRP * 64;           // bytes per staged f-row (32c fp16)
    constexpr int BUFB  = 4 * ROWB;           // bytes per LDS buffer
    constexpr int NSTG  = 4 * 16 * TRP;       // f16x2 units per tile
    constexpr int KPT   = (NSTG + 255) / 256; // units per thread
    constexpr int NTILES = NTB * 257 * 4;

    __shared__ char ldsb[2 * BUFB];

    const int tid  = threadIdx.x;
    const int lane = tid & 63;
    const int wave = tid >> 6;
    const int oh   = wave & 1;   // o-half
    const int frw  = wave >> 1;  // output f-row within tile

    // A fragments + bias: once per persistent block
    f16x8 a[NTAPS];
    {
        const f16* ap = Ap + oh * 512 + lane * 8;
        #pragma unroll
        for (int tap = 0; tap < NTAPS; ++tap)
            a[tap] = *reinterpret_cast<const f16x8*>(ap + tap * 1024);
    }
    const int og = oh * 16 + ((lane >> 4) << 2);
    float bs[4];
    #pragma unroll
    for (int r = 0; r < 4; ++r) bs[r] = bias[og + r];

    // swizzled LDS read bases (buffer offset added per tile)
    int baddr[KW];
    {
        int tln = lane & 15;
        int c0  = (lane >> 4) << 3;
        #pragma unroll
        for (int kw = 0; kw < KW; ++kw) {
            int trow = tln * STRIDE + kw;
            int byte = ((frw * TRP + trow) * 32 + c0) * 2;
            byte ^= ((trow >> 1) & 3) << 4;
            byte ^= ((trow >> 3) & 1) << 6;
            baddr[kw] = byte;
        }
    }

    float sv0[KPT], sv1[KPT];

    auto issue = [&](int tile) {
        int tb = tile % NTB; int r1 = tile / NTB;
        int fblk = r1 % 257; int b = r1 / 257;
        int f0 = fblk * 2;
        int tbase = tb * NT * STRIDE - PW;
        const float* inb = in + (size_t)b * 32 * NBINS * Tin;
        #pragma unroll
        for (int k = 0; k < KPT; ++k) {
            int u = tid + k * 256;
            float v0 = 0.f, v1 = 0.f;
            if (KPT * 256 == NSTG || u < NSTG) {
                int trow = u % TRP; int cf = u / TRP;
                int cp = (cf & 15) << 1; int fr = cf >> 4;
                int fi = f0 - 1 + fr;
                int ti = tbase + trow;
                if (fi >= 0 && fi < NBINS && ti >= 0 && ti < Tin) {
                    const float* p = inb + ((size_t)cp * NBINS + fi) * Tin + ti;
                    v0 = p[0];
                    v1 = p[(size_t)NBINS * Tin];
                }
            }
            sv0[k] = v0; sv1[k] = v1;
        }
    };
    auto write_stage = [&](int bufsel) {
        #pragma unroll
        for (int k = 0; k < KPT; ++k) {
            int u = tid + k * 256;
            if (KPT * 256 == NSTG || u < NSTG) {
                int trow = u % TRP; int cf = u / TRP;
                int cp = (cf & 15) << 1; int fr = cf >> 4;
                int byte = ((fr * TRP + trow) * 32 + cp) * 2;
                byte ^= ((trow >> 1) & 3) << 4;
                byte ^= ((trow >> 3) & 1) << 6;
                f16x2 h = __builtin_bit_cast(f16x2,
                              __builtin_amdgcn_cvt_pkrtz(sv0[k], sv1[k]));
                *reinterpret_cast<f16x2*>(ldsb + bufsel * BUFB + byte) = h;
            }
        }
    };

    int tile = blockIdx.x;
    if (tile >= NTILES) return;
    issue(tile);
    write_stage(0);
    asm volatile("s_waitcnt lgkmcnt(0)" ::: "memory");
    __builtin_amdgcn_s_barrier();
    int cur = 0;

    for (; tile < NTILES; tile += gridDim.x) {
        int nxt = tile + gridDim.x;
        bool have_next = nxt < NTILES;
        if (have_next) issue(nxt);   // loads stay in flight through compute

        int tb = tile % NTB; int r1 = tile / NTB;
        int fblk = r1 % 257; int b = r1 / 257;
        int f0 = fblk * 2; int t0 = tb * NT;

        f32x4 acc[4];
        #pragma unroll
        for (int nf = 0; nf < 4; ++nf) acc[nf] = (f32x4){0.f, 0.f, 0.f, 0.f};

        #pragma unroll
        for (int df = 0; df < 3; ++df) {
            #pragma unroll
            for (int kw = 0; kw < KW; ++kw) {
                f16x8 af = a[df * KW + kw];
                #pragma unroll
                for (int nf = 0; nf < 4; ++nf) {
                    f16x8 bf = *reinterpret_cast<const f16x8*>(
                        ldsb + cur * BUFB + baddr[kw] + df * ROWB + nf * (16 * STRIDE * 64));
                    acc[nf] = __builtin_amdgcn_mfma_f32_16x16x32_f16(af, bf, acc[nf], 0, 0, 0);
                }
            }
        }

        int f = f0 + frw;
        if (f < NBINS) {
            int tl = lane & 15;
            #pragma unroll
            for (int nf = 0; nf < 4; ++nf) {
                int t = t0 + nf * 16 + tl;
                if (t < Tout) {
                    #pragma unroll
                    for (int r = 0; r < 4; ++r) {
                        float v = acc[nf][r] + bs[r];
                        if (DO_LRELU) v = (v > 0.f) ? v : 0.1f * v;
                        out[(((size_t)b * 32 + og + r) * NBINS + f) * Tout + t] = v;
                    }
                }
            }
        }

        if (have_next) {
            write_stage(cur ^ 1);
            asm volatile("s_waitcnt lgkmcnt(0)" ::: "memory");
            __builtin_amdgcn_s_barrier();
            cur ^= 1;
        }
    }
}

// ------------------------------------------------------------ final conv ----
__global__ __launch_bounds__(256) void convo_kernel(const float* __restrict__ in,
                                                    const float* __restrict__ wn,
                                                    const float* __restrict__ bias,
                                                    float* __restrict__ f5,
                                                    float* __restrict__ flat)
{
    int idx = blockIdx.x * 256 + threadIdx.x;
    if (idx >= 4 * NBINS * 101) return;
    int t = idx % 101;
    int rem = idx / 101;
    int f = rem % NBINS;
    int b = rem / NBINS;

    float a = bias[0];
    const float* inb = in + (size_t)b * 32 * NBINS * 101;
    for (int c = 0; c < 32; ++c) {
        #pragma unroll
        for (int df = 0; df < 3; ++df) {
            int fi = f + df - 1;
            if (fi < 0 || fi >= NBINS) continue;
            #pragma unroll
            for (int kw = 0; kw < 3; ++kw) {
                int ti = t + kw - 1;
                if (ti < 0 || ti >= 101) continue;
                a = fmaf(inb[((size_t)c * NBINS + fi) * 101 + ti], wn[(c * 3 + df) * 3 + kw], a);
            }
        }
    }
    f5[idx] = a;
    flat[idx] = a;
}

// ------------------------------------------------------------------ launch --
extern "C" void kernel_launch(void* const* d_in, const int* in_sizes, int n_in,
                              void* d_out, int out_size, void* d_ws, size_t ws_size,
                              hipStream_t stream)
{
    const float* y  = (const float*)d_in[0];
    const float* v0 = (const float*)d_in[1];
    const float* g0 = (const float*)d_in[2];
    const float* b0 = (const float*)d_in[3];
    const float* v1 = (const float*)d_in[4];
    const float* g1 = (const float*)d_in[5];
    const float* b1 = (const float*)d_in[6];
    const float* v2 = (const float*)d_in[7];
    const float* g2 = (const float*)d_in[8];
    const float* b2 = (const float*)d_in[9];
    const float* v3 = (const float*)d_in[10];
    const float* g3 = (const float*)d_in[11];
    const float* b3 = (const float*)d_in[12];
    const float* v4 = (const float*)d_in[13];
    const float* g4 = (const float*)d_in[14];
    const float* b4 = (const float*)d_in[15];
    const float* vo = (const float*)d_in[16];
    const float* go = (const float*)d_in[17];
    const float* bo = (const float*)d_in[18];

    float* out = (float*)d_out;
    float* ws  = (float*)d_ws;

    const size_t SFLAT = (size_t)4 * NBINS * 101;
    const size_t NF0   = (size_t)4 * 32 * NBINS * 801;
    const size_t NF1   = (size_t)4 * 32 * NBINS * 401;
    const size_t NF2   = (size_t)4 * 32 * NBINS * 201;
    const size_t NF3   = (size_t)4 * 32 * NBINS * 101;
    float* oflat = out;
    float* f0 = out + SFLAT;
    float* f1 = f0 + NF0;
    float* f2 = f1 + NF1;
    float* f3 = f2 + NF2;
    float* f4 = f3 + NF3;
    float* f5 = f4 + NF3;

    // mag stashed in (not-yet-written) fmap1 region; consumed before conv1 writes it
    float* mag = f1;

    size_t off = 0;
    float* w0n = ws + off; off += 1568;
    float* w1n = ws + off; off += 27648;
    float* w2n = ws + off; off += 27648;
    float* w3n = ws + off; off += 27648;
    float* w4n = ws + off; off += 9216;
    float* won = ws + off; off += 288;
    f16* A1 = (f16*)(ws + off);
    f16* A2 = A1 + 27648;
    f16* A3 = A2 + 27648;
    f16* A4 = A3 + 27648;

    wnorm_kernel<<<32, 256, 0, stream>>>(v0, g0, w0n, 49);
    wnorm_kernel<<<32, 256, 0, stream>>>(v1, g1, w1n, 864);
    wnorm_kernel<<<32, 256, 0, stream>>>(v2, g2, w2n, 864);
    wnorm_kernel<<<32, 256, 0, stream>>>(v3, g3, w3n, 864);
    wnorm_kernel<<<32, 256, 0, stream>>>(v4, g4, w4n, 288);
    wnorm_kernel<<< 1, 256, 0, stream>>>(vo, go, won, 288);

    packA_kernel<9><<<108, 256, 0, stream>>>(w1n, A1);
    packA_kernel<9><<<108, 256, 0, stream>>>(w2n, A2);
    packA_kernel<9><<<108, 256, 0, stream>>>(w3n, A3);
    packA_kernel<3><<< 36, 256, 0, stream>>>(w4n, A4);

    stft_kernel<<<dim3(NFRAMES, 4), 512, 0, stream>>>(y, mag);

    double sh4 = -(1000.0 * log(0.001 * (5.0 / 7.0)) - 1000.0 * log(0.001)); // 336.472...
    double sh5 = -(1000.0 * log(0.001 * (6.0 / 7.0)) - 1000.0 * log(0.001)); // 154.150...
    float fr4 = (float)(sh4 - floor(sh4));
    float fr5 = (float)(sh5 - floor(sh5));

    harmonic_kernel<<<dim3(NBINS, 4), 256, 0, stream>>>(mag, w0n, b0, f0, fr4, fr5);

    conv_mfma_persist<9, 2, 4, 7, true><<<512, 256, 0, stream>>>(f0, A1, b1, f1, 801, 401);
    conv_mfma_persist<9, 2, 4, 4, true><<<512, 256, 0, stream>>>(f1, A2, b2, f2, 401, 201);
    conv_mfma_persist<9, 2, 4, 2, true><<<512, 256, 0, stream>>>(f2, A3, b3, f3, 201, 101);
    conv_mfma_persist<3, 1, 1, 2, true><<<512, 256, 0, stream>>>(f3, A4, b4, f4, 101, 101);

    convo_kernel<<<(int)((4 * NBINS * 101 + 255) / 256), 256, 0, stream>>>(f4, won, bo, f5, oflat);
}

// Round 6
// 518.547 us; speedup vs baseline: 2.0360x; 2.0360x over previous
//
#include <hip/hip_runtime.h>
#include <math.h>

#define T_SAMPLES 96000
#define NFRAMES 801
#define NBINS 513
#define EPS32 1.1920928955078125e-07f

typedef _Float16 f16;
typedef f16 f16x2 __attribute__((ext_vector_type(2)));
typedef f16 f16x8 __attribute__((ext_vector_type(8)));
typedef float f32x4 __attribute__((ext_vector_type(4)));

// ---------------------------------------------------------------- STFT ----
__global__ __launch_bounds__(512) void stft_kernel(const float* __restrict__ y,
                                                   float* __restrict__ mag)
{
    int t = blockIdx.x;   // frame 0..800
    int b = blockIdx.y;   // batch 0..3
    int tid = threadIdx.x;

    __shared__ float2 buf[2][1024];

    const float* yb = y + (size_t)b * T_SAMPLES;
    for (int n = tid; n < 1024; n += 512) {
        int j = t * 120 + n - 512;          // reflect pad 512 both sides
        if (j < 0) j = -j;
        if (j >= T_SAMPLES) j = 2 * T_SAMPLES - 2 - j;
        float v = yb[j];
        int np_ = n - 212;                  // window placed at lp=212, len 600
        float w = 0.0f;
        if (np_ >= 0 && np_ < 600)
            w = 0.5f * (1.0f - cospif((float)np_ * (1.0f / 300.0f)));
        buf[0][n] = make_float2(v * w, 0.0f);
    }
    __syncthreads();

    int srcb = 0;
    #pragma unroll
    for (int stage = 0; stage < 10; ++stage) {
        int m  = 1 << stage;
        int jm = (tid >> stage) << stage;   // j*m
        float jf = (float)jm * (1.0f / 512.0f);
        float wr = cospif(jf);
        float wi = -sinpif(jf);             // e^{-i pi j/l}
        float2 a  = buf[srcb][tid];
        float2 bb = buf[srcb][tid + 512];
        float2 s  = make_float2(a.x + bb.x, a.y + bb.y);
        float2 d  = make_float2(a.x - bb.x, a.y - bb.y);
        float2 dw = make_float2(d.x * wr - d.y * wi, d.x * wi + d.y * wr);
        buf[srcb ^ 1][tid + jm]     = s;
        buf[srcb ^ 1][tid + jm + m] = dw;
        __syncthreads();
        srcb ^= 1;
    }

    float2 v = buf[srcb][tid];
    float msq = v.x * v.x + v.y * v.y;
    mag[((size_t)b * NBINS + tid) * NFRAMES + t] = sqrtf(fmaxf(msq, EPS32));
    if (tid == 0) {
        float2 v5 = buf[srcb][512];
        float m5 = v5.x * v5.x + v5.y * v5.y;
        mag[((size_t)b * NBINS + 512) * NFRAMES + t] = sqrtf(fmaxf(m5, EPS32));
    }
}

// -------------------------------------------------- fused weight prep ----
// One kernel does all weight-norms + fp16 A-packing.
// Blocks 0..31: A1 (v1)  | 32..63: A2 (v2) | 64..95: A3 (v3)
// 96..127: A4 (v4, KW=3) | 128..159: w0n fp32 | 160: won fp32
__global__ __launch_bounds__(256) void prep_kernel(
    const float* __restrict__ v0, const float* __restrict__ g0,
    const float* __restrict__ v1, const float* __restrict__ g1,
    const float* __restrict__ v2, const float* __restrict__ g2,
    const float* __restrict__ v3, const float* __restrict__ g3,
    const float* __restrict__ v4, const float* __restrict__ g4,
    const float* __restrict__ vo, const float* __restrict__ go,
    float* __restrict__ w0n, float* __restrict__ won,
    f16* __restrict__ A1, f16* __restrict__ A2,
    f16* __restrict__ A3, f16* __restrict__ A4)
{
    int blk = blockIdx.x;
    int tid = threadIdx.x;

    const float *v, *g; f16* Ap = nullptr; float* outf = nullptr;
    int o, per_o, KW = 9;
    if (blk < 32)        { v = v1; g = g1; Ap = A1; o = blk;       per_o = 864; }
    else if (blk < 64)   { v = v2; g = g2; Ap = A2; o = blk - 32;  per_o = 864; }
    else if (blk < 96)   { v = v3; g = g3; Ap = A3; o = blk - 64;  per_o = 864; }
    else if (blk < 128)  { v = v4; g = g4; Ap = A4; o = blk - 96;  per_o = 288; KW = 3; }
    else if (blk < 160)  { v = v0; g = g0; outf = w0n; o = blk - 128; per_o = 49; }
    else                 { v = vo; g = go; outf = won; o = 0;        per_o = 288; }

    const float* vv = v + (size_t)o * per_o;
    __shared__ float red[256];
    float s = 0.f;
    for (int i = tid; i < per_o; i += 256) { float x = vv[i]; s = fmaf(x, x, s); }
    red[tid] = s;
    __syncthreads();
    for (int k = 128; k > 0; k >>= 1) {
        if (tid < k) red[tid] += red[tid + k];
        __syncthreads();
    }
    float scale = g[o] / sqrtf(red[0]);

    if (outf) {
        for (int i = tid; i < per_o; i += 256)
            outf[(size_t)o * per_o + i] = vv[i] * scale;
    } else {
        int oh = o >> 4;
        for (int i = tid; i < per_o; i += 256) {
            // i enumerates (tap, c): tap = i>>5, c = i&31
            int tap = i >> 5;
            int c   = i & 31;
            int df  = tap / KW, kw = tap - df * KW;
            float val = vv[(c * 3 + df) * KW + kw] * scale;
            int l = ((c >> 3) << 4) + (o & 15);
            int j = c & 7;
            Ap[(((tap * 2 + oh) * 64 + l) << 3) + j] = (f16)val;
        }
    }
}

// -------------------------------------------------------- harmonic conv ----
__global__ __launch_bounds__(256) void harmonic_kernel(const float* __restrict__ mag,
                                                       const float* __restrict__ wn,
                                                       const float* __restrict__ bias,
                                                       float* __restrict__ out,
                                                       float fr4, float fr5)
{
    int f = blockIdx.x;
    int b = blockIdx.y;
    int tid = threadIdx.x;

    __shared__ float rows[3][808];

    const float* mb = mag + (size_t)b * NBINS * NFRAMES;

    for (int i = tid; i < 808; i += 256) {
        int tt = i - 3;
        bool ok = (tt >= 0) && (tt < NFRAMES);
        float m336 = (ok && f >= 336) ? mb[(size_t)(f - 336) * NFRAMES + tt] : 0.f;
        float m337 = (ok && f >= 337) ? mb[(size_t)(f - 337) * NFRAMES + tt] : 0.f;
        float m154 = (ok && f >= 154) ? mb[(size_t)(f - 154) * NFRAMES + tt] : 0.f;
        float m155 = (ok && f >= 155) ? mb[(size_t)(f - 155) * NFRAMES + tt] : 0.f;
        float m0   = ok ? mb[(size_t)f * NFRAMES + tt] : 0.f;
        rows[0][i] = (1.f - fr4) * m336 + fr4 * m337;
        rows[1][i] = (1.f - fr5) * m154 + fr5 * m155;
        rows[2][i] = m0;
    }
    __syncthreads();

    int t0 = tid * 4;
    float win[3][10];
    #pragma unroll
    for (int r = 0; r < 3; ++r)
        #pragma unroll
        for (int k = 0; k < 10; ++k) {
            int idx = t0 + k; if (idx > 807) idx = 807;
            win[r][k] = rows[r][idx];
        }

    bool full = (t0 + 3 < NFRAMES);
    bool any  = (t0 < NFRAMES);
    if (!any) return;

    size_t obase = (((size_t)b * 32) * NBINS + f) * NFRAMES + t0;
    for (int o = 0; o < 32; ++o) {
        float acc0 = bias[o], acc1 = acc0, acc2 = acc0, acc3 = acc0;
        #pragma unroll
        for (int r = 0; r < 3; ++r) {
            const float* wr = wn + (o * 7 + 4 + r) * 7;
            #pragma unroll
            for (int kw = 0; kw < 7; ++kw) {
                float w = wr[kw];
                acc0 = fmaf(win[r][kw],     w, acc0);
                acc1 = fmaf(win[r][kw + 1], w, acc1);
                acc2 = fmaf(win[r][kw + 2], w, acc2);
                acc3 = fmaf(win[r][kw + 3], w, acc3);
            }
        }
        acc0 = (acc0 > 0.f) ? acc0 : 0.1f * acc0;
        acc1 = (acc1 > 0.f) ? acc1 : 0.1f * acc1;
        acc2 = (acc2 > 0.f) ? acc2 : 0.1f * acc2;
        acc3 = (acc3 > 0.f) ? acc3 : 0.1f * acc3;
        float* p = out + obase + (size_t)o * NBINS * NFRAMES;
        if (full) {
            f32x4 v = {acc0, acc1, acc2, acc3};
            *reinterpret_cast<f32x4*>(p) = v;
        } else {
            int nrem = NFRAMES - t0;           // 1..3
            p[0] = acc0;
            if (nrem > 1) p[1] = acc1;
            if (nrem > 2) p[2] = acc2;
        }
    }
}

// ----------------------------------------------------------- MFMA conv ----
// 32ch -> 32ch, kernel 3 x KW, freq pad 1, time pad PW, time stride STRIDE.
// Block: 8 waves = {o-half} x {4 f-rows}; tile 32o x 4f x 64t; stages 6
// input f-rows (1.5x amplification vs 2.0x for the 2-row variant).
// LDS layout [frow][trow][c] fp16 with XOR swizzle (invariant under the
// df/nf offset immediates, bits >= 7).
template<int KW, int STRIDE, int PW, bool DO_LRELU>
__global__ __launch_bounds__(512, 4) void conv_mfma_kernel(
    const float* __restrict__ in, const f16* __restrict__ Ap,
    const float* __restrict__ bias, float* __restrict__ out,
    int Tin, int Tout)
{
    constexpr int NT    = 64;
    constexpr int TR    = NT * STRIDE + KW - 1;
    constexpr int TRP   = (TR + 1) & ~1;
    constexpr int NTAPS = 3 * KW;
    constexpr int ROWB  = TRP * 64;            // bytes per staged f-row
    constexpr int NROWS = 6;
    __shared__ f16 lds[NROWS * TRP * 32];

    const int tid = threadIdx.x;
    const int t0  = blockIdx.x * NT;
    const int f0  = blockIdx.y * 4;
    const int b   = blockIdx.z;

    const float* inb = in + (size_t)b * 32 * NBINS * Tin;
    const int tbase = t0 * STRIDE - PW;
    char* ldsb = (char*)&lds[0];

    // ---- stage: rows f0-1 .. f0+4, transposed + swizzled, fp16 pairs
    constexpr int NSTG = NROWS * 16 * TRP;
    for (int i = tid; i < NSTG; i += 512) {
        int trow = i % TRP;
        int cf   = i / TRP;
        int cp   = (cf & 15) << 1;   // even channel
        int fr   = cf >> 4;          // 0..5
        int fi = f0 - 1 + fr;
        int ti = tbase + trow;
        float v0 = 0.f, v1 = 0.f;
        if (fi >= 0 && fi < NBINS && ti >= 0 && ti < Tin) {
            const float* p = inb + ((size_t)cp * NBINS + fi) * Tin + ti;
            v0 = p[0];
            v1 = p[(size_t)NBINS * Tin];
        }
        f16x2 h; h[0] = (f16)v0; h[1] = (f16)v1;
        int byte = ((fr * TRP + trow) * 32 + cp) * 2;
        byte ^= ((trow >> 1) & 3) << 4;
        byte ^= ((trow >> 3) & 1) << 6;
        *reinterpret_cast<f16x2*>(ldsb + byte) = h;
    }

    const int lane = tid & 63;
    const int wave = tid >> 6;
    const int oh   = wave & 1;   // o-half
    const int frw  = wave >> 1;  // output f-row within tile (0..3)

    // A fragments (global, L2-resident, coalesced 16B/lane)
    f16x8 a[NTAPS];
    {
        const f16* ap = Ap + oh * 512 + lane * 8;
        #pragma unroll
        for (int tap = 0; tap < NTAPS; ++tap)
            a[tap] = *reinterpret_cast<const f16x8*>(ap + tap * 1024);
    }

    // per-kw swizzled base addresses (df/nf via offset immediates)
    int baddr[KW];
    {
        int tln = lane & 15;
        int c0  = (lane >> 4) << 3;
        #pragma unroll
        for (int kw = 0; kw < KW; ++kw) {
            int trow = tln * STRIDE + kw;
            int byte = ((frw * TRP + trow) * 32 + c0) * 2;
            byte ^= ((trow >> 1) & 3) << 4;
            byte ^= ((trow >> 3) & 1) << 6;
            baddr[kw] = byte;
        }
    }

    __syncthreads();

    f32x4 acc[4];
    #pragma unroll
    for (int nf = 0; nf < 4; ++nf) acc[nf] = (f32x4){0.f, 0.f, 0.f, 0.f};

    #pragma unroll
    for (int df = 0; df < 3; ++df) {
        #pragma unroll
        for (int kw = 0; kw < KW; ++kw) {
            f16x8 af = a[df * KW + kw];
            #pragma unroll
            for (int nf = 0; nf < 4; ++nf) {
                f16x8 bf = *reinterpret_cast<const f16x8*>(
                    ldsb + (baddr[kw] + df * ROWB + nf * (16 * STRIDE * 64)));
                acc[nf] = __builtin_amdgcn_mfma_f32_16x16x32_f16(af, bf, acc[nf], 0, 0, 0);
            }
        }
    }

    const int f = f0 + frw;
    if (f < NBINS) {
        const int og = oh * 16 + ((lane >> 4) << 2);
        const int tl = lane & 15;
        float bs[4];
        #pragma unroll
        for (int r = 0; r < 4; ++r) bs[r] = bias[og + r];
        #pragma unroll
        for (int nf = 0; nf < 4; ++nf) {
            int t = t0 + nf * 16 + tl;
            if (t < Tout) {
                #pragma unroll
                for (int r = 0; r < 4; ++r) {
                    float v = acc[nf][r] + bs[r];
                    if (DO_LRELU) v = (v > 0.f) ? v : 0.1f * v;
                    out[(((size_t)b * 32 + og + r) * NBINS + f) * Tout + t] = v;
                }
            }
        }
    }
}

// ------------------------------------------------------------ final conv ----
__global__ __launch_bounds__(256) void convo_kernel(const float* __restrict__ in,
                                                    const float* __restrict__ wn,
                                                    const float* __restrict__ bias,
                                                    float* __restrict__ f5,
                                                    float* __restrict__ flat)
{
    int idx = blockIdx.x * 256 + threadIdx.x;
    if (idx >= 4 * NBINS * 101) return;
    int t = idx % 101;
    int rem = idx / 101;
    int f = rem % NBINS;
    int b = rem / NBINS;

    float a = bias[0];
    const float* inb = in + (size_t)b * 32 * NBINS * 101;
    for (int c = 0; c < 32; ++c) {
        #pragma unroll
        for (int df = 0; df < 3; ++df) {
            int fi = f + df - 1;
            if (fi < 0 || fi >= NBINS) continue;
            #pragma unroll
            for (int kw = 0; kw < 3; ++kw) {
                int ti = t + kw - 1;
                if (ti < 0 || ti >= 101) continue;
                a = fmaf(inb[((size_t)c * NBINS + fi) * 101 + ti], wn[(c * 3 + df) * 3 + kw], a);
            }
        }
    }
    f5[idx] = a;
    flat[idx] = a;
}

// ------------------------------------------------------------------ launch --
extern "C" void kernel_launch(void* const* d_in, const int* in_sizes, int n_in,
                              void* d_out, int out_size, void* d_ws, size_t ws_size,
                              hipStream_t stream)
{
    const float* y  = (const float*)d_in[0];
    const float* v0 = (const float*)d_in[1];
    const float* g0 = (const float*)d_in[2];
    const float* b0 = (const float*)d_in[3];
    const float* v1 = (const float*)d_in[4];
    const float* g1 = (const float*)d_in[5];
    const float* b1 = (const float*)d_in[6];
    const float* v2 = (const float*)d_in[7];
    const float* g2 = (const float*)d_in[8];
    const float* b2 = (const float*)d_in[9];
    const float* v3 = (const float*)d_in[10];
    const float* g3 = (const float*)d_in[11];
    const float* b3 = (const float*)d_in[12];
    const float* v4 = (const float*)d_in[13];
    const float* g4 = (const float*)d_in[14];
    const float* b4 = (const float*)d_in[15];
    const float* vo = (const float*)d_in[16];
    const float* go = (const float*)d_in[17];
    const float* bo = (const float*)d_in[18];

    float* out = (float*)d_out;
    float* ws  = (float*)d_ws;

    const size_t SFLAT = (size_t)4 * NBINS * 101;
    const size_t NF0   = (size_t)4 * 32 * NBINS * 801;
    const size_t NF1   = (size_t)4 * 32 * NBINS * 401;
    const size_t NF2   = (size_t)4 * 32 * NBINS * 201;
    const size_t NF3   = (size_t)4 * 32 * NBINS * 101;
    float* oflat = out;
    float* f0 = out + SFLAT;
    float* f1 = f0 + NF0;
    float* f2 = f1 + NF1;
    float* f3 = f2 + NF2;
    float* f4 = f3 + NF3;
    float* f5 = f4 + NF3;

    // mag stashed in (not-yet-written) fmap1 region; consumed before conv1 writes it
    float* mag = f1;

    size_t off = 0;
    float* w0n = ws + off; off += 1568;
    float* won = ws + off; off += 288;
    f16* A1 = (f16*)(ws + off);
    f16* A2 = A1 + 27648;
    f16* A3 = A2 + 27648;
    f16* A4 = A3 + 27648;   // 9216 elements

    prep_kernel<<<161, 256, 0, stream>>>(v0, g0, v1, g1, v2, g2, v3, g3,
                                         v4, g4, vo, go, w0n, won,
                                         A1, A2, A3, A4);

    stft_kernel<<<dim3(NFRAMES, 4), 512, 0, stream>>>(y, mag);

    double sh4 = -(1000.0 * log(0.001 * (5.0 / 7.0)) - 1000.0 * log(0.001)); // 336.472...
    double sh5 = -(1000.0 * log(0.001 * (6.0 / 7.0)) - 1000.0 * log(0.001)); // 154.150...
    float fr4 = (float)(sh4 - floor(sh4));
    float fr5 = (float)(sh5 - floor(sh5));

    harmonic_kernel<<<dim3(NBINS, 4), 256, 0, stream>>>(mag, w0n, b0, f0, fr4, fr5);

    conv_mfma_kernel<9, 2, 4, true><<<dim3(7, 129, 4), 512, 0, stream>>>(f0, A1, b1, f1, 801, 401);
    conv_mfma_kernel<9, 2, 4, true><<<dim3(4, 129, 4), 512, 0, stream>>>(f1, A2, b2, f2, 401, 201);
    conv_mfma_kernel<9, 2, 4, true><<<dim3(2, 129, 4), 512, 0, stream>>>(f2, A3, b3, f3, 201, 101);
    conv_mfma_kernel<3, 1, 1, true><<<dim3(2, 129, 4), 512, 0, stream>>>(f3, A4, b4, f4, 101, 101);

    convo_kernel<<<(int)((4 * NBINS * 101 + 255) / 256), 256, 0, stream>>>(f4, won, bo, f5, oflat);
}

// Round 7
// 498.608 us; speedup vs baseline: 2.1174x; 1.0400x over previous
//
#include <hip/hip_runtime.h>
#include <math.h>

#define T_SAMPLES 96000
#define NFRAMES 801
#define NBINS 513
#define EPS32 1.1920928955078125e-07f

typedef _Float16 f16;
typedef f16 f16x2 __attribute__((ext_vector_type(2)));
typedef f16 f16x4 __attribute__((ext_vector_type(4)));
typedef f16 f16x8 __attribute__((ext_vector_type(8)));
typedef float f32x4 __attribute__((ext_vector_type(4)));
typedef float f32x16 __attribute__((ext_vector_type(16)));

// ---------------------------------------------------------------- STFT ----
__global__ __launch_bounds__(512) void stft_kernel(const float* __restrict__ y,
                                                   float* __restrict__ mag)
{
    int t = blockIdx.x;   // frame 0..800
    int b = blockIdx.y;   // batch 0..3
    int tid = threadIdx.x;

    __shared__ float2 buf[2][1024];

    const float* yb = y + (size_t)b * T_SAMPLES;
    for (int n = tid; n < 1024; n += 512) {
        int j = t * 120 + n - 512;          // reflect pad 512 both sides
        if (j < 0) j = -j;
        if (j >= T_SAMPLES) j = 2 * T_SAMPLES - 2 - j;
        float v = yb[j];
        int np_ = n - 212;                  // window placed at lp=212, len 600
        float w = 0.0f;
        if (np_ >= 0 && np_ < 600)
            w = 0.5f * (1.0f - cospif((float)np_ * (1.0f / 300.0f)));
        buf[0][n] = make_float2(v * w, 0.0f);
    }
    __syncthreads();

    int srcb = 0;
    #pragma unroll
    for (int stage = 0; stage < 10; ++stage) {
        int m  = 1 << stage;
        int jm = (tid >> stage) << stage;   // j*m
        float jf = (float)jm * (1.0f / 512.0f);
        float wr = cospif(jf);
        float wi = -sinpif(jf);             // e^{-i pi j/l}
        float2 a  = buf[srcb][tid];
        float2 bb = buf[srcb][tid + 512];
        float2 s  = make_float2(a.x + bb.x, a.y + bb.y);
        float2 d  = make_float2(a.x - bb.x, a.y - bb.y);
        float2 dw = make_float2(d.x * wr - d.y * wi, d.x * wi + d.y * wr);
        buf[srcb ^ 1][tid + jm]     = s;
        buf[srcb ^ 1][tid + jm + m] = dw;
        __syncthreads();
        srcb ^= 1;
    }

    float2 v = buf[srcb][tid];
    float msq = v.x * v.x + v.y * v.y;
    mag[((size_t)b * NBINS + tid) * NFRAMES + t] = sqrtf(fmaxf(msq, EPS32));
    if (tid == 0) {
        float2 v5 = buf[srcb][512];
        float m5 = v5.x * v5.x + v5.y * v5.y;
        mag[((size_t)b * NBINS + 512) * NFRAMES + t] = sqrtf(fmaxf(m5, EPS32));
    }
}

// -------------------------------------------------- fused weight prep ----
// Blocks 0..31: A1 | 32..63: A2 | 64..95: A3 | 96..127: A4 (KW=3)
// 128..159: w0n fp32 | 160: won fp32
// A-pack (32x32x16 frag-linear):
//   Ap[((tap*2 + ch)*64 + l)*8 + j] = w[o = l&31][c = ch*16 + (l>>5)*8 + j][df][kw]
__global__ __launch_bounds__(256) void prep_kernel(
    const float* __restrict__ v0, const float* __restrict__ g0,
    const float* __restrict__ v1, const float* __restrict__ g1,
    const float* __restrict__ v2, const float* __restrict__ g2,
    const float* __restrict__ v3, const float* __restrict__ g3,
    const float* __restrict__ v4, const float* __restrict__ g4,
    const float* __restrict__ vo, const float* __restrict__ go,
    float* __restrict__ w0n, float* __restrict__ won,
    f16* __restrict__ A1, f16* __restrict__ A2,
    f16* __restrict__ A3, f16* __restrict__ A4)
{
    int blk = blockIdx.x;
    int tid = threadIdx.x;

    const float *v, *g; f16* Ap = nullptr; float* outf = nullptr;
    int o, per_o, KW = 9;
    if (blk < 32)        { v = v1; g = g1; Ap = A1; o = blk;       per_o = 864; }
    else if (blk < 64)   { v = v2; g = g2; Ap = A2; o = blk - 32;  per_o = 864; }
    else if (blk < 96)   { v = v3; g = g3; Ap = A3; o = blk - 64;  per_o = 864; }
    else if (blk < 128)  { v = v4; g = g4; Ap = A4; o = blk - 96;  per_o = 288; KW = 3; }
    else if (blk < 160)  { v = v0; g = g0; outf = w0n; o = blk - 128; per_o = 49; }
    else                 { v = vo; g = go; outf = won; o = 0;        per_o = 288; }

    const float* vv = v + (size_t)o * per_o;
    __shared__ float red[256];
    float s = 0.f;
    for (int i = tid; i < per_o; i += 256) { float x = vv[i]; s = fmaf(x, x, s); }
    red[tid] = s;
    __syncthreads();
    for (int k = 128; k > 0; k >>= 1) {
        if (tid < k) red[tid] += red[tid + k];
        __syncthreads();
    }
    float scale = g[o] / sqrtf(red[0]);

    if (outf) {
        for (int i = tid; i < per_o; i += 256)
            outf[(size_t)o * per_o + i] = vv[i] * scale;
    } else {
        for (int i = tid; i < per_o; i += 256) {
            int tap = i >> 5;
            int c   = i & 31;
            int df  = tap / KW, kw = tap - df * KW;
            float val = vv[(c * 3 + df) * KW + kw] * scale;
            int l = ((c >> 3) & 1) * 32 + o;     // l&31 = o, l>>5 = c bit3
            int ch = c >> 4;
            int j = c & 7;
            Ap[(((tap * 2 + ch) * 64 + l) << 3) + j] = (f16)val;
        }
    }
}

// -------------------------------------------------------- harmonic conv ----
__global__ __launch_bounds__(256) void harmonic_kernel(const float* __restrict__ mag,
                                                       const float* __restrict__ wn,
                                                       const float* __restrict__ bias,
                                                       float* __restrict__ out,
                                                       float fr4, float fr5)
{
    int f = blockIdx.x;
    int b = blockIdx.y;
    int tid = threadIdx.x;

    __shared__ float rows[3][808];

    const float* mb = mag + (size_t)b * NBINS * NFRAMES;

    for (int i = tid; i < 808; i += 256) {
        int tt = i - 3;
        bool ok = (tt >= 0) && (tt < NFRAMES);
        float m336 = (ok && f >= 336) ? mb[(size_t)(f - 336) * NFRAMES + tt] : 0.f;
        float m337 = (ok && f >= 337) ? mb[(size_t)(f - 337) * NFRAMES + tt] : 0.f;
        float m154 = (ok && f >= 154) ? mb[(size_t)(f - 154) * NFRAMES + tt] : 0.f;
        float m155 = (ok && f >= 155) ? mb[(size_t)(f - 155) * NFRAMES + tt] : 0.f;
        float m0   = ok ? mb[(size_t)f * NFRAMES + tt] : 0.f;
        rows[0][i] = (1.f - fr4) * m336 + fr4 * m337;
        rows[1][i] = (1.f - fr5) * m154 + fr5 * m155;
        rows[2][i] = m0;
    }
    __syncthreads();

    int t0 = tid * 4;
    float win[3][10];
    #pragma unroll
    for (int r = 0; r < 3; ++r)
        #pragma unroll
        for (int k = 0; k < 10; ++k) {
            int idx = t0 + k; if (idx > 807) idx = 807;
            win[r][k] = rows[r][idx];
        }

    bool full = (t0 + 3 < NFRAMES);
    bool any  = (t0 < NFRAMES);
    if (!any) return;

    size_t obase = (((size_t)b * 32) * NBINS + f) * NFRAMES + t0;
    for (int o = 0; o < 32; ++o) {
        float acc0 = bias[o], acc1 = acc0, acc2 = acc0, acc3 = acc0;
        #pragma unroll
        for (int r = 0; r < 3; ++r) {
            const float* wr = wn + (o * 7 + 4 + r) * 7;
            #pragma unroll
            for (int kw = 0; kw < 7; ++kw) {
                float w = wr[kw];
                acc0 = fmaf(win[r][kw],     w, acc0);
                acc1 = fmaf(win[r][kw + 1], w, acc1);
                acc2 = fmaf(win[r][kw + 2], w, acc2);
                acc3 = fmaf(win[r][kw + 3], w, acc3);
            }
        }
        acc0 = (acc0 > 0.f) ? acc0 : 0.1f * acc0;
        acc1 = (acc1 > 0.f) ? acc1 : 0.1f * acc1;
        acc2 = (acc2 > 0.f) ? acc2 : 0.1f * acc2;
        acc3 = (acc3 > 0.f) ? acc3 : 0.1f * acc3;
        float* p = out + obase + (size_t)o * NBINS * NFRAMES;
        if (full) {
            f32x4 v = {acc0, acc1, acc2, acc3};
            *reinterpret_cast<f32x4*>(p) = v;
        } else {
            int nrem = NFRAMES - t0;           // 1..3
            p[0] = acc0;
            if (nrem > 1) p[1] = acc1;
            if (nrem > 2) p[2] = acc2;
        }
    }
}

// ------------------------------------------------------- MFMA conv v3 ----
// 32ch -> 32ch via mfma_f32_32x32x16_f16. 4 waves/block; wave = one output
// f-row, full 32 o x 64 t. LDS [frow][trow][c] fp16, XOR swizzle bits 4,5,6
// <- (trow+TOFF) bits 1,2,3.
// PAD_IN==0: stage from fp32 [o][f][t] (scatter+cvt).
// PAD_IN>0 : stage = pure memcpy from padded pre-swizzled fp16 copy
//            [b][f][TpadIn][32c] (written by the previous conv's epilogue).
// PAD_OUT>0: epilogue also writes the fp16 copy for the next conv.
template<int KW, int STRIDE, int PW, int PAD_IN, int PAD_OUT, bool DO_LRELU>
__global__ __launch_bounds__(256, 3) void conv_v3(
    const float* __restrict__ inF, const f16* __restrict__ inC,
    const f16* __restrict__ Ap, const float* __restrict__ bias,
    float* __restrict__ out, f16* __restrict__ outC,
    int Tin, int Tout, int TpadIn, int TpadOut)
{
    constexpr int NT    = 64;
    constexpr int TR    = NT * STRIDE + KW - 1;
    constexpr int TRP   = (TR + 1) & ~1;
    constexpr int ROWB  = TRP * 64;
    constexpr int TOFF  = PAD_IN ? ((PAD_IN - PW) & 15) : 0;
    constexpr int NFOFF = 32 * STRIDE * 64;

    __shared__ char ldsb[6 * TRP * 64];

    const int tid  = threadIdx.x;
    const int lane = tid & 63;
    const int wave = tid >> 6;          // = output f-row within tile
    const int t0   = blockIdx.x * NT;
    const int f0   = blockIdx.y * 4;
    const int b    = blockIdx.z;
    const int tbase = t0 * STRIDE - PW;

    // ---------------- stage ----------------
    if constexpr (PAD_IN == 0) {
        constexpr int NSTG = 6 * 16 * TRP;   // f16x2 units
        const float* inb = inF + (size_t)b * 32 * NBINS * Tin;
        for (int i = tid; i < NSTG; i += 256) {
            int trow = i % TRP;
            int cf   = i / TRP;
            int cp   = (cf & 15) << 1;
            int fr   = cf >> 4;
            int fi = f0 - 1 + fr;
            int ti = tbase + trow;
            float va = 0.f, vb = 0.f;
            if (fi >= 0 && fi < NBINS && ti >= 0 && ti < Tin) {
                const float* p = inb + ((size_t)cp * NBINS + fi) * Tin + ti;
                va = p[0];
                vb = p[(size_t)NBINS * Tin];
            }
            f16x2 h; h[0] = (f16)va; h[1] = (f16)vb;
            int byte = fr * ROWB + trow * 64 + cp * 2;
            byte ^= ((trow >> 1) & 3) << 4;
            byte ^= ((trow >> 3) & 1) << 6;
            *reinterpret_cast<f16x2*>(ldsb + byte) = h;
        }
    } else {
        constexpr int SL = TRP * 4;          // 16B slots per f-row
        constexpr int NS = 6 * SL;
        const int g0 = tbase + PAD_IN;
        #pragma unroll
        for (int it = 0; it < (NS + 255) / 256; ++it) {
            int slot = tid + it * 256;
            if (slot < NS) {
                int fr = slot / SL;
                int s  = slot - fr * SL;
                int fi = f0 - 1 + fr;
                f16x8 v;
                if (fi >= 0 && fi < NBINS) {
                    size_t idx = (((size_t)(b * NBINS + fi)) * TpadIn + g0) * 32 + (size_t)s * 8;
                    v = *reinterpret_cast<const f16x8*>(inC + idx);
                } else {
                    #pragma unroll
                    for (int j = 0; j < 8; ++j) v[j] = (f16)0.f;
                }
                *reinterpret_cast<f16x8*>(ldsb + slot * 16) = v;
            }
        }
    }

    // swizzled LDS read bases
    const int tln = lane & 31;
    const int hi  = lane >> 5;
    int baddr0[KW];
    #pragma unroll
    for (int kw = 0; kw < KW; ++kw) {
        int trow = tln * STRIDE + kw;
        int x = trow + TOFF;
        int swz = (((x >> 1) & 3) << 4) | (((x >> 3) & 1) << 6);
        baddr0[kw] = (trow * 64 + hi * 16) ^ swz;
    }

    __syncthreads();

    f32x16 acc[2];
    #pragma unroll
    for (int nf = 0; nf < 2; ++nf)
        #pragma unroll
        for (int r = 0; r < 16; ++r) acc[nf][r] = 0.f;

    const char* lrow = ldsb + wave * ROWB;   // wave's f-row window starts at fr=wave
    #pragma unroll
    for (int df = 0; df < 3; ++df) {
        f16x8 a[KW * 2];
        #pragma unroll
        for (int kw = 0; kw < KW; ++kw)
            #pragma unroll
            for (int ch = 0; ch < 2; ++ch)
                a[kw * 2 + ch] = *reinterpret_cast<const f16x8*>(
                    Ap + (((df * KW + kw) * 2 + ch) << 9) + lane * 8);
        #pragma unroll
        for (int kw = 0; kw < KW; ++kw) {
            #pragma unroll
            for (int ch = 0; ch < 2; ++ch) {
                #pragma unroll
                for (int nf = 0; nf < 2; ++nf) {
                    f16x8 bf = *reinterpret_cast<const f16x8*>(
                        lrow + ((baddr0[kw] ^ (ch << 5)) + df * ROWB + nf * NFOFF));
                    acc[nf] = __builtin_amdgcn_mfma_f32_32x32x16_f16(a[kw * 2 + ch], bf, acc[nf], 0, 0, 0);
                }
            }
        }
    }

    // ---------------- epilogue ----------------
    const int f = f0 + wave;
    if (f >= NBINS) return;

    float bs[16];
    #pragma unroll
    for (int r = 0; r < 16; ++r)
        bs[r] = bias[4 * hi + 8 * (r >> 2) + (r & 3)];

    char* crow = nullptr;
    if constexpr (PAD_OUT > 0)
        crow = (char*)outC + ((size_t)(b * NBINS + f)) * TpadOut * 64;

    #pragma unroll
    for (int nf = 0; nf < 2; ++nf) {
        int t = t0 + nf * 32 + tln;
        bool vt = (t < Tout);
        float vals[16];
        #pragma unroll
        for (int r = 0; r < 16; ++r) {
            float v = acc[nf][r] + bs[r];
            if (DO_LRELU) v = (v > 0.f) ? v : 0.1f * v;
            vals[r] = v;
        }
        if (vt) {
            #pragma unroll
            for (int r = 0; r < 16; ++r) {
                int o = 4 * hi + 8 * (r >> 2) + (r & 3);
                out[(((size_t)b * 32 + o) * NBINS + f) * Tout + t] = vals[r];
            }
        }
        if constexpr (PAD_OUT > 0) {
            int tg = t + PAD_OUT;
            int swz = (((tg >> 1) & 3) << 4) | (((tg >> 3) & 1) << 6);
            int rowbyte = (tg * 64) ^ swz;
            #pragma unroll
            for (int q = 0; q < 4; ++q) {
                f16x4 hv;
                if (vt) {
                    #pragma unroll
                    for (int r = 0; r < 4; ++r) hv[r] = (f16)vals[4 * q + r];
                } else {
                    #pragma unroll
                    for (int r = 0; r < 4; ++r) hv[r] = (f16)0.f;
                }
                int byte = rowbyte ^ ((4 * hi + 8 * q) << 1);
                *reinterpret_cast<f16x4*>(crow + byte) = hv;
            }
        }
    }
    // left pad zeros (tg in [0, PAD_OUT))
    if constexpr (PAD_OUT > 0) {
        if (blockIdx.x == 0 && lane < PAD_OUT * 4) {
            int tgp = lane >> 2, oct = lane & 3;
            f16x8 z;
            #pragma unroll
            for (int j = 0; j < 8; ++j) z[j] = (f16)0.f;
            *reinterpret_cast<f16x8*>(crow + tgp * 64 + oct * 16) = z;
        }
    }
}

// ------------------------------------------------------------ final conv ----
__global__ __launch_bounds__(256) void convo_kernel(const float* __restrict__ in,
                                                    const float* __restrict__ wn,
                                                    const float* __restrict__ bias,
                                                    float* __restrict__ f5,
                                                    float* __restrict__ flat)
{
    int idx = blockIdx.x * 256 + threadIdx.x;
    if (idx >= 4 * NBINS * 101) return;
    int t = idx % 101;
    int rem = idx / 101;
    int f = rem % NBINS;
    int b = rem / NBINS;

    float a = bias[0];
    const float* inb = in + (size_t)b * 32 * NBINS * 101;
    for (int c = 0; c < 32; ++c) {
        #pragma unroll
        for (int df = 0; df < 3; ++df) {
            int fi = f + df - 1;
            if (fi < 0 || fi >= NBINS) continue;
            #pragma unroll
            for (int kw = 0; kw < 3; ++kw) {
                int ti = t + kw - 1;
                if (ti < 0 || ti >= 101) continue;
                a = fmaf(inb[((size_t)c * NBINS + fi) * 101 + ti], wn[(c * 3 + df) * 3 + kw], a);
            }
        }
    }
    f5[idx] = a;
    flat[idx] = a;
}

// ------------------------------------------------------------------ launch --
extern "C" void kernel_launch(void* const* d_in, const int* in_sizes, int n_in,
                              void* d_out, int out_size, void* d_ws, size_t ws_size,
                              hipStream_t stream)
{
    const float* y  = (const float*)d_in[0];
    const float* v0 = (const float*)d_in[1];
    const float* g0 = (const float*)d_in[2];
    const float* b0 = (const float*)d_in[3];
    const float* v1 = (const float*)d_in[4];
    const float* g1 = (const float*)d_in[5];
    const float* b1 = (const float*)d_in[6];
    const float* v2 = (const float*)d_in[7];
    const float* g2 = (const float*)d_in[8];
    const float* b2 = (const float*)d_in[9];
    const float* v3 = (const float*)d_in[10];
    const float* g3 = (const float*)d_in[11];
    const float* b3 = (const float*)d_in[12];
    const float* v4 = (const float*)d_in[13];
    const float* g4 = (const float*)d_in[14];
    const float* b4 = (const float*)d_in[15];
    const float* vo = (const float*)d_in[16];
    const float* go = (const float*)d_in[17];
    const float* bo = (const float*)d_in[18];

    float* out = (float*)d_out;
    float* ws  = (float*)d_ws;

    const size_t SFLAT = (size_t)4 * NBINS * 101;
    const size_t NF0   = (size_t)4 * 32 * NBINS * 801;
    const size_t NF1   = (size_t)4 * 32 * NBINS * 401;
    const size_t NF2   = (size_t)4 * 32 * NBINS * 201;
    const size_t NF3   = (size_t)4 * 32 * NBINS * 101;
    float* oflat = out;
    float* f0 = out + SFLAT;
    float* f1 = f0 + NF0;
    float* f2 = f1 + NF1;
    float* f3 = f2 + NF2;
    float* f4 = f3 + NF3;
    float* f5 = f4 + NF3;

    // mag stashed in (not-yet-written) fmap1 region; consumed before conv1 writes it
    float* mag = f1;

    // ws layout: fp32 small weights, fp16 A-packs, fp16 activation copies
    size_t off = 0;
    float* w0n = ws + off; off += 1568;
    float* won = ws + off; off += 288;
    f16* A1 = (f16*)(ws + off);
    f16* A2 = A1 + 27648;
    f16* A3 = A2 + 27648;
    f16* A4 = A3 + 27648;               // 9216 elements
    f16* f1c = A4 + 9216;               // [4][513][520][32] fp16, PAD=4
    const int TP1 = 520;
    f16* f2c = f1c + (size_t)4 * NBINS * TP1 * 32;   // [4][513][264][32], PAD=4
    const int TP2 = 264;
    f16* f3c = f2c + (size_t)4 * NBINS * TP2 * 32;   // [4][513][136][32], PAD=5
    const int TP3 = 136;

    prep_kernel<<<161, 256, 0, stream>>>(v0, g0, v1, g1, v2, g2, v3, g3,
                                         v4, g4, vo, go, w0n, won,
                                         A1, A2, A3, A4);

    stft_kernel<<<dim3(NFRAMES, 4), 512, 0, stream>>>(y, mag);

    double sh4 = -(1000.0 * log(0.001 * (5.0 / 7.0)) - 1000.0 * log(0.001)); // 336.472...
    double sh5 = -(1000.0 * log(0.001 * (6.0 / 7.0)) - 1000.0 * log(0.001)); // 154.150...
    float fr4 = (float)(sh4 - floor(sh4));
    float fr5 = (float)(sh5 - floor(sh5));

    harmonic_kernel<<<dim3(NBINS, 4), 256, 0, stream>>>(mag, w0n, b0, f0, fr4, fr5);

    // conv1: fp32 input (f0), writes f1 + f1c copy
    conv_v3<9, 2, 4, 0, 4, true><<<dim3(7, 129, 4), 256, 0, stream>>>(
        f0, nullptr, A1, b1, f1, f1c, 801, 401, 0, TP1);
    // conv2: fp16 copy input, writes f2 + f2c
    conv_v3<9, 2, 4, 4, 4, true><<<dim3(4, 129, 4), 256, 0, stream>>>(
        nullptr, f1c, A2, b2, f2, f2c, 401, 201, TP1, TP2);
    // conv3: fp16 copy input, writes f3 + f3c (PAD_OUT=5 keeps conv4's window pair-aligned)
    conv_v3<9, 2, 4, 4, 5, true><<<dim3(2, 129, 4), 256, 0, stream>>>(
        nullptr, f2c, A3, b3, f3, f3c, 201, 101, TP2, TP3);
    // conv4: fp16 copy input, fp32 output only
    conv_v3<3, 1, 1, 5, 0, true><<<dim3(2, 129, 4), 256, 0, stream>>>(
        nullptr, f3c, A4, b4, f4, nullptr, 101, 101, TP3, 0);

    convo_kernel<<<(int)((4 * NBINS * 101 + 255) / 256), 256, 0, stream>>>(f4, won, bo, f5, oflat);
}

// Round 8
// 461.740 us; speedup vs baseline: 2.2865x; 1.0798x over previous
//
#include <hip/hip_runtime.h>
#include <math.h>

#define T_SAMPLES 96000
#define NFRAMES 801
#define NBINS 513
#define EPS32 1.1920928955078125e-07f

typedef _Float16 f16;
typedef f16 f16x2 __attribute__((ext_vector_type(2)));
typedef f16 f16x4 __attribute__((ext_vector_type(4)));
typedef f16 f16x8 __attribute__((ext_vector_type(8)));
typedef float f32x4 __attribute__((ext_vector_type(4)));
typedef float f32x16 __attribute__((ext_vector_type(16)));

// ---------------------------------------------------------------- STFT ----
__global__ __launch_bounds__(512) void stft_kernel(const float* __restrict__ y,
                                                   float* __restrict__ mag)
{
    int t = blockIdx.x;   // frame 0..800
    int b = blockIdx.y;   // batch 0..3
    int tid = threadIdx.x;

    __shared__ float2 buf[2][1024];

    const float* yb = y + (size_t)b * T_SAMPLES;
    for (int n = tid; n < 1024; n += 512) {
        int j = t * 120 + n - 512;          // reflect pad 512 both sides
        if (j < 0) j = -j;
        if (j >= T_SAMPLES) j = 2 * T_SAMPLES - 2 - j;
        float v = yb[j];
        int np_ = n - 212;                  // window placed at lp=212, len 600
        float w = 0.0f;
        if (np_ >= 0 && np_ < 600)
            w = 0.5f * (1.0f - cospif((float)np_ * (1.0f / 300.0f)));
        buf[0][n] = make_float2(v * w, 0.0f);
    }
    __syncthreads();

    int srcb = 0;
    #pragma unroll
    for (int stage = 0; stage < 10; ++stage) {
        int m  = 1 << stage;
        int jm = (tid >> stage) << stage;   // j*m
        float jf = (float)jm * (1.0f / 512.0f);
        float wr = cospif(jf);
        float wi = -sinpif(jf);             // e^{-i pi j/l}
        float2 a  = buf[srcb][tid];
        float2 bb = buf[srcb][tid + 512];
        float2 s  = make_float2(a.x + bb.x, a.y + bb.y);
        float2 d  = make_float2(a.x - bb.x, a.y - bb.y);
        float2 dw = make_float2(d.x * wr - d.y * wi, d.x * wi + d.y * wr);
        buf[srcb ^ 1][tid + jm]     = s;
        buf[srcb ^ 1][tid + jm + m] = dw;
        __syncthreads();
        srcb ^= 1;
    }

    float2 v = buf[srcb][tid];
    float msq = v.x * v.x + v.y * v.y;
    mag[((size_t)b * NBINS + tid) * NFRAMES + t] = sqrtf(fmaxf(msq, EPS32));
    if (tid == 0) {
        float2 v5 = buf[srcb][512];
        float m5 = v5.x * v5.x + v5.y * v5.y;
        mag[((size_t)b * NBINS + 512) * NFRAMES + t] = sqrtf(fmaxf(m5, EPS32));
    }
}

// -------------------------------------------------- fused weight prep ----
// Blocks 0..31: A1 | 32..63: A2 | 64..95: A3 | 96..127: A4 (KW=3)
// 128..159: w0n fp32 | 160: won fp32
__global__ __launch_bounds__(256) void prep_kernel(
    const float* __restrict__ v0, const float* __restrict__ g0,
    const float* __restrict__ v1, const float* __restrict__ g1,
    const float* __restrict__ v2, const float* __restrict__ g2,
    const float* __restrict__ v3, const float* __restrict__ g3,
    const float* __restrict__ v4, const float* __restrict__ g4,
    const float* __restrict__ vo, const float* __restrict__ go,
    float* __restrict__ w0n, float* __restrict__ won,
    f16* __restrict__ A1, f16* __restrict__ A2,
    f16* __restrict__ A3, f16* __restrict__ A4)
{
    int blk = blockIdx.x;
    int tid = threadIdx.x;

    const float *v, *g; f16* Ap = nullptr; float* outf = nullptr;
    int o, per_o, KW = 9;
    if (blk < 32)        { v = v1; g = g1; Ap = A1; o = blk;       per_o = 864; }
    else if (blk < 64)   { v = v2; g = g2; Ap = A2; o = blk - 32;  per_o = 864; }
    else if (blk < 96)   { v = v3; g = g3; Ap = A3; o = blk - 64;  per_o = 864; }
    else if (blk < 128)  { v = v4; g = g4; Ap = A4; o = blk - 96;  per_o = 288; KW = 3; }
    else if (blk < 160)  { v = v0; g = g0; outf = w0n; o = blk - 128; per_o = 49; }
    else                 { v = vo; g = go; outf = won; o = 0;        per_o = 288; }

    const float* vv = v + (size_t)o * per_o;
    __shared__ float red[256];
    float s = 0.f;
    for (int i = tid; i < per_o; i += 256) { float x = vv[i]; s = fmaf(x, x, s); }
    red[tid] = s;
    __syncthreads();
    for (int k = 128; k > 0; k >>= 1) {
        if (tid < k) red[tid] += red[tid + k];
        __syncthreads();
    }
    float scale = g[o] / sqrtf(red[0]);

    if (outf) {
        for (int i = tid; i < per_o; i += 256)
            outf[(size_t)o * per_o + i] = vv[i] * scale;
    } else {
        for (int i = tid; i < per_o; i += 256) {
            int tap = i >> 5;
            int c   = i & 31;
            int df  = tap / KW, kw = tap - df * KW;
            float val = vv[(c * 3 + df) * KW + kw] * scale;
            int l = ((c >> 3) & 1) * 32 + o;     // l&31 = o, l>>5 = c bit3
            int ch = c >> 4;
            int j = c & 7;
            Ap[(((tap * 2 + ch) * 64 + l) << 3) + j] = (f16)val;
        }
    }
}

// -------------------------------------------------------- harmonic conv ----
// One block per (f, b). Stage 3 blended rows in LDS; each thread computes
// one t for all 32 output channels; writes fp32 fmap + padded swizzle-baked
// fp16 copy f0c [b][f][tg=t+4][32c] (TP0=904; zero pads tg<4 and tg>=805).
__global__ __launch_bounds__(256) void harmonic_kernel(const float* __restrict__ mag,
                                                       const float* __restrict__ wn,
                                                       const float* __restrict__ bias,
                                                       float* __restrict__ out,
                                                       f16* __restrict__ f0c,
                                                       float fr4, float fr5)
{
    int f = blockIdx.x;
    int b = blockIdx.y;
    int tid = threadIdx.x;

    __shared__ float rows[3][808];

    const float* mb = mag + (size_t)b * NBINS * NFRAMES;

    for (int i = tid; i < 808; i += 256) {
        int tt = i - 3;
        bool ok = (tt >= 0) && (tt < NFRAMES);
        float m336 = (ok && f >= 336) ? mb[(size_t)(f - 336) * NFRAMES + tt] : 0.f;
        float m337 = (ok && f >= 337) ? mb[(size_t)(f - 337) * NFRAMES + tt] : 0.f;
        float m154 = (ok && f >= 154) ? mb[(size_t)(f - 154) * NFRAMES + tt] : 0.f;
        float m155 = (ok && f >= 155) ? mb[(size_t)(f - 155) * NFRAMES + tt] : 0.f;
        float m0   = ok ? mb[(size_t)f * NFRAMES + tt] : 0.f;
        rows[0][i] = (1.f - fr4) * m336 + fr4 * m337;
        rows[1][i] = (1.f - fr5) * m154 + fr5 * m155;
        rows[2][i] = m0;
    }
    __syncthreads();

    char* crow = (char*)f0c + ((size_t)(b * NBINS + f)) * 904 * 64;

    // left pad zeros: tg in [0,4)
    if (tid < 16) {
        int tg = tid >> 2, q = tid & 3;
        int swz = (((tg >> 1) & 3) << 4) | (((tg >> 3) & 1) << 6);
        f16x8 z;
        #pragma unroll
        for (int j = 0; j < 8; ++j) z[j] = (f16)0.f;
        *reinterpret_cast<f16x8*>(crow + ((tg * 64 + q * 16) ^ swz)) = z;
    }

    #pragma unroll
    for (int chunk = 0; chunk < 4; ++chunk) {
        int t = chunk * 256 + tid;
        if (t < NFRAMES) {
            float win[3][7];
            #pragma unroll
            for (int r = 0; r < 3; ++r)
                #pragma unroll
                for (int k = 0; k < 7; ++k)
                    win[r][k] = rows[r][t + k];

            float vals[32];
            #pragma unroll
            for (int o = 0; o < 32; ++o) {
                float a = bias[o];
                #pragma unroll
                for (int r = 0; r < 3; ++r) {
                    const float* wr = wn + (o * 7 + 4 + r) * 7;
                    #pragma unroll
                    for (int kw = 0; kw < 7; ++kw)
                        a = fmaf(win[r][kw], wr[kw], a);
                }
                vals[o] = (a > 0.f) ? a : 0.1f * a;
            }

            #pragma unroll
            for (int o = 0; o < 32; ++o)
                out[(((size_t)b * 32 + o) * NBINS + f) * (size_t)NFRAMES + t] = vals[o];

            int tg = t + 4;
            int swz = (((tg >> 1) & 3) << 4) | (((tg >> 3) & 1) << 6);
            #pragma unroll
            for (int q = 0; q < 4; ++q) {
                f16x8 h;
                #pragma unroll
                for (int j = 0; j < 8; ++j) h[j] = (f16)vals[q * 8 + j];
                *reinterpret_cast<f16x8*>(crow + ((tg * 64 + q * 16) ^ swz)) = h;
            }
        } else if (t < 900) {                 // right pad zeros: tg in [805,904)
            int tg = t + 4;
            int swz = (((tg >> 1) & 3) << 4) | (((tg >> 3) & 1) << 6);
            f16x8 z;
            #pragma unroll
            for (int j = 0; j < 8; ++j) z[j] = (f16)0.f;
            #pragma unroll
            for (int q = 0; q < 4; ++q)
                *reinterpret_cast<f16x8*>(crow + ((tg * 64 + q * 16) ^ swz)) = z;
        }
    }
}

// ------------------------------------------------------- MFMA conv v3 ----
// 32ch -> 32ch via mfma_f32_32x32x16_f16. 4 waves/block; wave = one output
// f-row, full 32 o x 64 t. LDS [frow][trow][c] fp16, XOR swizzle bits 4,5,6
// <- (trow+TOFF) bits 1,2,3.
// PAD_IN==0: stage from fp32 [o][f][t] (scatter+cvt).
// PAD_IN>0 : stage = pure memcpy from padded pre-swizzled fp16 copy
//            [b][f][TpadIn][32c] (written by the previous conv's epilogue).
// PAD_OUT>0: epilogue also writes the fp16 copy for the next conv.
template<int KW, int STRIDE, int PW, int PAD_IN, int PAD_OUT, bool DO_LRELU>
__global__ __launch_bounds__(256, 3) void conv_v3(
    const float* __restrict__ inF, const f16* __restrict__ inC,
    const f16* __restrict__ Ap, const float* __restrict__ bias,
    float* __restrict__ out, f16* __restrict__ outC,
    int Tin, int Tout, int TpadIn, int TpadOut)
{
    constexpr int NT    = 64;
    constexpr int TR    = NT * STRIDE + KW - 1;
    constexpr int TRP   = (TR + 1) & ~1;
    constexpr int ROWB  = TRP * 64;
    constexpr int TOFF  = PAD_IN ? ((PAD_IN - PW) & 15) : 0;
    constexpr int NFOFF = 32 * STRIDE * 64;

    __shared__ char ldsb[6 * TRP * 64];

    const int tid  = threadIdx.x;
    const int lane = tid & 63;
    const int wave = tid >> 6;          // = output f-row within tile
    const int t0   = blockIdx.x * NT;
    const int f0   = blockIdx.y * 4;
    const int b    = blockIdx.z;
    const int tbase = t0 * STRIDE - PW;

    // ---------------- stage ----------------
    if constexpr (PAD_IN == 0) {
        constexpr int NSTG = 6 * 16 * TRP;   // f16x2 units
        const float* inb = inF + (size_t)b * 32 * NBINS * Tin;
        for (int i = tid; i < NSTG; i += 256) {
            int trow = i % TRP;
            int cf   = i / TRP;
            int cp   = (cf & 15) << 1;
            int fr   = cf >> 4;
            int fi = f0 - 1 + fr;
            int ti = tbase + trow;
            float va = 0.f, vb = 0.f;
            if (fi >= 0 && fi < NBINS && ti >= 0 && ti < Tin) {
                const float* p = inb + ((size_t)cp * NBINS + fi) * Tin + ti;
                va = p[0];
                vb = p[(size_t)NBINS * Tin];
            }
            f16x2 h; h[0] = (f16)va; h[1] = (f16)vb;
            int byte = fr * ROWB + trow * 64 + cp * 2;
            byte ^= ((trow >> 1) & 3) << 4;
            byte ^= ((trow >> 3) & 1) << 6;
            *reinterpret_cast<f16x2*>(ldsb + byte) = h;
        }
    } else {
        constexpr int SL = TRP * 4;          // 16B slots per f-row
        constexpr int NS = 6 * SL;
        const int g0 = tbase + PAD_IN;
        #pragma unroll
        for (int it = 0; it < (NS + 255) / 256; ++it) {
            int slot = tid + it * 256;
            if (slot < NS) {
                int fr = slot / SL;
                int s  = slot - fr * SL;
                int fi = f0 - 1 + fr;
                f16x8 v;
                if (fi >= 0 && fi < NBINS) {
                    size_t idx = (((size_t)(b * NBINS + fi)) * TpadIn + g0) * 32 + (size_t)s * 8;
                    v = *reinterpret_cast<const f16x8*>(inC + idx);
                } else {
                    #pragma unroll
                    for (int j = 0; j < 8; ++j) v[j] = (f16)0.f;
                }
                *reinterpret_cast<f16x8*>(ldsb + slot * 16) = v;
            }
        }
    }

    // swizzled LDS read bases
    const int tln = lane & 31;
    const int hi  = lane >> 5;
    int baddr0[KW];
    #pragma unroll
    for (int kw = 0; kw < KW; ++kw) {
        int trow = tln * STRIDE + kw;
        int x = trow + TOFF;
        int swz = (((x >> 1) & 3) << 4) | (((x >> 3) & 1) << 6);
        baddr0[kw] = (trow * 64 + hi * 16) ^ swz;
    }

    __syncthreads();

    f32x16 acc[2];
    #pragma unroll
    for (int nf = 0; nf < 2; ++nf)
        #pragma unroll
        for (int r = 0; r < 16; ++r) acc[nf][r] = 0.f;

    const char* lrow = ldsb + wave * ROWB;   // wave's f-row window starts at fr=wave
    #pragma unroll
    for (int df = 0; df < 3; ++df) {
        f16x8 a[KW * 2];
        #pragma unroll
        for (int kw = 0; kw < KW; ++kw)
            #pragma unroll
            for (int ch = 0; ch < 2; ++ch)
                a[kw * 2 + ch] = *reinterpret_cast<const f16x8*>(
                    Ap + (((df * KW + kw) * 2 + ch) << 9) + lane * 8);
        #pragma unroll
        for (int kw = 0; kw < KW; ++kw) {
            #pragma unroll
            for (int ch = 0; ch < 2; ++ch) {
                #pragma unroll
                for (int nf = 0; nf < 2; ++nf) {
                    f16x8 bf = *reinterpret_cast<const f16x8*>(
                        lrow + ((baddr0[kw] ^ (ch << 5)) + df * ROWB + nf * NFOFF));
                    acc[nf] = __builtin_amdgcn_mfma_f32_32x32x16_f16(a[kw * 2 + ch], bf, acc[nf], 0, 0, 0);
                }
            }
        }
    }

    // ---------------- epilogue ----------------
    const int f = f0 + wave;
    if (f >= NBINS) return;

    float bs[16];
    #pragma unroll
    for (int r = 0; r < 16; ++r)
        bs[r] = bias[4 * hi + 8 * (r >> 2) + (r & 3)];

    char* crow = nullptr;
    if constexpr (PAD_OUT > 0)
        crow = (char*)outC + ((size_t)(b * NBINS + f)) * TpadOut * 64;

    #pragma unroll
    for (int nf = 0; nf < 2; ++nf) {
        int t = t0 + nf * 32 + tln;
        bool vt = (t < Tout);
        float vals[16];
        #pragma unroll
        for (int r = 0; r < 16; ++r) {
            float v = acc[nf][r] + bs[r];
            if (DO_LRELU) v = (v > 0.f) ? v : 0.1f * v;
            vals[r] = v;
        }
        if (vt) {
            #pragma unroll
            for (int r = 0; r < 16; ++r) {
                int o = 4 * hi + 8 * (r >> 2) + (r & 3);
                out[(((size_t)b * 32 + o) * NBINS + f) * Tout + t] = vals[r];
            }
        }
        if constexpr (PAD_OUT > 0) {
            int tg = t + PAD_OUT;
            int swz = (((tg >> 1) & 3) << 4) | (((tg >> 3) & 1) << 6);
            int rowbyte = (tg * 64) ^ swz;
            #pragma unroll
            for (int q = 0; q < 4; ++q) {
                f16x4 hv;
                if (vt) {
                    #pragma unroll
                    for (int r = 0; r < 4; ++r) hv[r] = (f16)vals[4 * q + r];
                } else {
                    #pragma unroll
                    for (int r = 0; r < 4; ++r) hv[r] = (f16)0.f;
                }
                int byte = rowbyte ^ ((4 * hi + 8 * q) << 1);
                *reinterpret_cast<f16x4*>(crow + byte) = hv;
            }
        }
    }
    // left pad zeros (tg in [0, PAD_OUT))
    if constexpr (PAD_OUT > 0) {
        if (blockIdx.x == 0 && lane < PAD_OUT * 4) {
            int tgp = lane >> 2, oct = lane & 3;
            f16x8 z;
            #pragma unroll
            for (int j = 0; j < 8; ++j) z[j] = (f16)0.f;
            *reinterpret_cast<f16x8*>(crow + tgp * 64 + oct * 16) = z;
        }
    }
}

// ------------------------------------------------------------ final conv ----
__global__ __launch_bounds__(256) void convo_kernel(const float* __restrict__ in,
                                                    const float* __restrict__ wn,
                                                    const float* __restrict__ bias,
                                                    float* __restrict__ f5,
                                                    float* __restrict__ flat)
{
    int idx = blockIdx.x * 256 + threadIdx.x;
    if (idx >= 4 * NBINS * 101) return;
    int t = idx % 101;
    int rem = idx / 101;
    int f = rem % NBINS;
    int b = rem / NBINS;

    float a = bias[0];
    const float* inb = in + (size_t)b * 32 * NBINS * 101;
    for (int c = 0; c < 32; ++c) {
        #pragma unroll
        for (int df = 0; df < 3; ++df) {
            int fi = f + df - 1;
            if (fi < 0 || fi >= NBINS) continue;
            #pragma unroll
            for (int kw = 0; kw < 3; ++kw) {
                int ti = t + kw - 1;
                if (ti < 0 || ti >= 101) continue;
                a = fmaf(inb[((size_t)c * NBINS + fi) * 101 + ti], wn[(c * 3 + df) * 3 + kw], a);
            }
        }
    }
    f5[idx] = a;
    flat[idx] = a;
}

// ------------------------------------------------------------------ launch --
extern "C" void kernel_launch(void* const* d_in, const int* in_sizes, int n_in,
                              void* d_out, int out_size, void* d_ws, size_t ws_size,
                              hipStream_t stream)
{
    const float* y  = (const float*)d_in[0];
    const float* v0 = (const float*)d_in[1];
    const float* g0 = (const float*)d_in[2];
    const float* b0 = (const float*)d_in[3];
    const float* v1 = (const float*)d_in[4];
    const float* g1 = (const float*)d_in[5];
    const float* b1 = (const float*)d_in[6];
    const float* v2 = (const float*)d_in[7];
    const float* g2 = (const float*)d_in[8];
    const float* b2 = (const float*)d_in[9];
    const float* v3 = (const float*)d_in[10];
    const float* g3 = (const float*)d_in[11];
    const float* b3 = (const float*)d_in[12];
    const float* v4 = (const float*)d_in[13];
    const float* g4 = (const float*)d_in[14];
    const float* b4 = (const float*)d_in[15];
    const float* vo = (const float*)d_in[16];
    const float* go = (const float*)d_in[17];
    const float* bo = (const float*)d_in[18];

    float* out = (float*)d_out;
    float* ws  = (float*)d_ws;

    const size_t SFLAT = (size_t)4 * NBINS * 101;
    const size_t NF0   = (size_t)4 * 32 * NBINS * 801;
    const size_t NF1   = (size_t)4 * 32 * NBINS * 401;
    const size_t NF2   = (size_t)4 * 32 * NBINS * 201;
    const size_t NF3   = (size_t)4 * 32 * NBINS * 101;
    float* oflat = out;
    float* f0 = out + SFLAT;
    float* f1 = f0 + NF0;
    float* f2 = f1 + NF1;
    float* f3 = f2 + NF2;
    float* f4 = f3 + NF3;
    float* f5 = f4 + NF3;

    // mag stashed in (not-yet-written) fmap1 region; consumed before conv1 writes it
    float* mag = f1;

    // ws layout: fp32 small weights, fp16 A-packs, fp16 activation copies
    size_t off = 0;
    float* w0n = ws + off; off += 1568;
    float* won = ws + off; off += 288;
    f16* A1 = (f16*)(ws + off);
    f16* A2 = A1 + 27648;
    f16* A3 = A2 + 27648;
    f16* A4 = A3 + 27648;               // 9216 elements
    f16* f0c = A4 + 9216;               // [4][513][904][32] fp16, PAD=4
    const int TP0 = 904;
    f16* f1c = f0c + (size_t)4 * NBINS * TP0 * 32;   // [4][513][520][32], PAD=4
    const int TP1 = 520;
    f16* f2c = f1c + (size_t)4 * NBINS * TP1 * 32;   // [4][513][264][32], PAD=4
    const int TP2 = 264;
    f16* f3c = f2c + (size_t)4 * NBINS * TP2 * 32;   // [4][513][136][32], PAD=5
    const int TP3 = 136;

    prep_kernel<<<161, 256, 0, stream>>>(v0, g0, v1, g1, v2, g2, v3, g3,
                                         v4, g4, vo, go, w0n, won,
                                         A1, A2, A3, A4);

    stft_kernel<<<dim3(NFRAMES, 4), 512, 0, stream>>>(y, mag);

    double sh4 = -(1000.0 * log(0.001 * (5.0 / 7.0)) - 1000.0 * log(0.001)); // 336.472...
    double sh5 = -(1000.0 * log(0.001 * (6.0 / 7.0)) - 1000.0 * log(0.001)); // 154.150...
    float fr4 = (float)(sh4 - floor(sh4));
    float fr5 = (float)(sh5 - floor(sh5));

    harmonic_kernel<<<dim3(NBINS, 4), 256, 0, stream>>>(mag, w0n, b0, f0, f0c, fr4, fr5);

    // conv1: fp16 copy input (f0c), writes f1 + f1c copy
    conv_v3<9, 2, 4, 4, 4, true><<<dim3(7, 129, 4), 256, 0, stream>>>(
        nullptr, f0c, A1, b1, f1, f1c, 801, 401, TP0, TP1);
    // conv2: fp16 copy input, writes f2 + f2c
    conv_v3<9, 2, 4, 4, 4, true><<<dim3(4, 129, 4), 256, 0, stream>>>(
        nullptr, f1c, A2, b2, f2, f2c, 401, 201, TP1, TP2);
    // conv3: fp16 copy input, writes f3 + f3c (PAD_OUT=5 keeps conv4's window pair-aligned)
    conv_v3<9, 2, 4, 4, 5, true><<<dim3(2, 129, 4), 256, 0, stream>>>(
        nullptr, f2c, A3, b3, f3, f3c, 201, 101, TP2, TP3);
    // conv4: fp16 copy input, fp32 output only
    conv_v3<3, 1, 1, 5, 0, true><<<dim3(2, 129, 4), 256, 0, stream>>>(
        nullptr, f3c, A4, b4, f4, nullptr, 101, 101, TP3, 0);

    convo_kernel<<<(int)((4 * NBINS * 101 + 255) / 256), 256, 0, stream>>>(f4, won, bo, f5, oflat);
}